// Round 1
// baseline (137.144 us; speedup 1.0000x reference)
//
#include <hip/hip_runtime.h>
#include <hip/hip_bf16.h>

#define B_ 8
#define T_ 2048
#define C_ 1024
#define HS_ 64

typedef float f32x4 __attribute__((ext_vector_type(4)));
typedef __bf16 bf16x8 __attribute__((ext_vector_type(8)));
typedef __bf16 bf16x4 __attribute__((ext_vector_type(4)));

// ---------------------------------------------------------------------------
// Kernel 1: transpose+scale weights into Wt[192][1024] bf16.
// n in [0,64): Wq column n, scaled by 1/32 (fold score scale C^-0.5 into q)
// n in [64,128): Wk column n-64 ; n in [128,192): Wv column n-128
// ---------------------------------------------------------------------------
__global__ __launch_bounds__(256) void wt_kernel(const float* __restrict__ Wq,
                                                 const float* __restrict__ Wk,
                                                 const float* __restrict__ Wv,
                                                 __bf16* __restrict__ wt) {
    int i = blockIdx.x * 256 + threadIdx.x;   // 0 .. 196607
    int n = i >> 10;
    int k = i & 1023;
    const float* W = (n < 64) ? Wq : (n < 128 ? Wk : Wv);
    int col = n & 63;
    float v = W[k * 64 + col];
    if (n < 64) v *= 0.03125f;
    wt[i] = (__bf16)v;
}

// ---------------------------------------------------------------------------
// Kernel 2: QKV projection. One wave per 16 rows of x (M=16384).
// acc tiles 0-3 = q cols 0-63, 4-7 = k cols, 8-11 = v cols.
// q,k stored [B*T][64] bf16; v stored transposed [B][64][T] bf16.
// ---------------------------------------------------------------------------
__global__ __launch_bounds__(256) void qkv_kernel(const float* __restrict__ x,
                                                  const __bf16* __restrict__ wt,
                                                  __bf16* __restrict__ q,
                                                  __bf16* __restrict__ k,
                                                  __bf16* __restrict__ vt) {
    int wid  = (blockIdx.x * 256 + threadIdx.x) >> 6;  // 0..1023
    int lane = threadIdx.x & 63;
    int lq = lane & 15;
    int lg = lane >> 4;
    int m0 = wid * 16;

    f32x4 acc[12];
#pragma unroll
    for (int t = 0; t < 12; ++t) acc[t] = (f32x4)0.0f;

    const float* xrow = x + (size_t)(m0 + lq) * C_;
    for (int k0 = 0; k0 < C_; k0 += 32) {
        int kk = k0 + lg * 8;
        float4 x0 = *(const float4*)(xrow + kk);
        float4 x1 = *(const float4*)(xrow + kk + 4);
        bf16x8 a;
        a[0] = (__bf16)x0.x; a[1] = (__bf16)x0.y; a[2] = (__bf16)x0.z; a[3] = (__bf16)x0.w;
        a[4] = (__bf16)x1.x; a[5] = (__bf16)x1.y; a[6] = (__bf16)x1.z; a[7] = (__bf16)x1.w;
#pragma unroll
        for (int t = 0; t < 12; ++t) {
            bf16x8 b = *(const bf16x8*)(wt + (size_t)(t * 16 + lq) * C_ + kk);
            acc[t] = __builtin_amdgcn_mfma_f32_16x16x32_bf16(a, b, acc[t], 0, 0, 0);
        }
    }

    // epilogue: q,k scattered bf16 stores; v packed transposed stores
    int bb  = m0 >> 11;     // batch
    int tt0 = m0 & 2047;    // t within batch
#pragma unroll
    for (int t = 0; t < 8; ++t) {
        __bf16* dst = (t < 4) ? q : k;
        int h = (t & 3) * 16 + lq;
#pragma unroll
        for (int r = 0; r < 4; ++r) {
            int row = m0 + lg * 4 + r;   // == b*2048 + t
            dst[(size_t)row * HS_ + h] = (__bf16)acc[t][r];
        }
    }
#pragma unroll
    for (int t = 8; t < 12; ++t) {
        int h = (t - 8) * 16 + lq;
        int trow = tt0 + lg * 4;
        bf16x4 pv;
#pragma unroll
        for (int r = 0; r < 4; ++r) pv[r] = (__bf16)acc[t][r];
        *(bf16x4*)(vt + ((size_t)bb * HS_ + h) * T_ + trow) = pv;
    }
}

// ---------------------------------------------------------------------------
// Kernel 3: causal flash attention. One wave per 16 queries.
// S tile = 16 queries x 32 keys via 4 MFMAs; online softmax; P relayout
// through per-wave LDS; PV via 4 MFMAs reading v^T.
// ---------------------------------------------------------------------------
__global__ __launch_bounds__(256) void attn_kernel(const __bf16* __restrict__ q,
                                                   const __bf16* __restrict__ k,
                                                   const __bf16* __restrict__ vt,
                                                   float* __restrict__ out) {
    // per-wave P staging: [16 rows][40] bf16 -> row stride 80 B (16B aligned,
    // only 2-way bank alias on b128 reads which is free)
    __shared__ __bf16 plds[4][16][40];

    int wu   = (blockIdx.x * 256 + threadIdx.x) >> 6;  // 0..1023
    int w    = threadIdx.x >> 6;
    int lane = threadIdx.x & 63;
    int lq = lane & 15;
    int lg = lane >> 4;

    int b  = wu >> 7;          // batch
    int t0 = (wu & 127) * 16;  // query block start

    const __bf16* qb = q  + ((size_t)b * T_ + t0) * HS_;
    const __bf16* kb = k  + (size_t)b * T_ * HS_;
    const __bf16* vb = vt + (size_t)b * HS_ * T_;

    // Q A-fragments (row = lane&15 -> query, k = (lane>>4)*8+j -> h)
    bf16x8 aq0 = *(const bf16x8*)(qb + (size_t)lq * HS_ + lg * 8);
    bf16x8 aq1 = *(const bf16x8*)(qb + (size_t)lq * HS_ + 32 + lg * 8);

    f32x4 o[4];
#pragma unroll
    for (int nt = 0; nt < 4; ++nt) o[nt] = (f32x4)0.0f;
    float m_s[4] = {-1e30f, -1e30f, -1e30f, -1e30f};
    float l_s[4] = {0.f, 0.f, 0.f, 0.f};

    int ntiles = (t0 + 47) >> 5;   // ceil((t0+16)/32)
    for (int kt = 0; kt < ntiles; ++kt) {
        int s0 = kt * 32;
        // S = Q K^T  (already scaled via Wq)
        f32x4 s[2];
#pragma unroll
        for (int ct = 0; ct < 2; ++ct) {
            const __bf16* kp = kb + (size_t)(s0 + ct * 16 + lq) * HS_;
            bf16x8 b0 = *(const bf16x8*)(kp + lg * 8);
            bf16x8 b1 = *(const bf16x8*)(kp + 32 + lg * 8);
            f32x4 a = (f32x4)0.0f;
            a = __builtin_amdgcn_mfma_f32_16x16x32_bf16(aq0, b0, a, 0, 0, 0);
            a = __builtin_amdgcn_mfma_f32_16x16x32_bf16(aq1, b1, a, 0, 0, 0);
            s[ct] = a;
        }
        // causal mask (only tiles overlapping the diagonal)
        if (s0 + 31 > t0) {
#pragma unroll
            for (int ct = 0; ct < 2; ++ct) {
                int scol = s0 + ct * 16 + lq;
#pragma unroll
                for (int r = 0; r < 4; ++r) {
                    int trow = t0 + lg * 4 + r;
                    if (scol > trow) s[ct][r] = -1e30f;
                }
            }
        }
        // online softmax
        float pm[4], mn[4], al[4];
#pragma unroll
        for (int r = 0; r < 4; ++r) pm[r] = fmaxf(s[0][r], s[1][r]);
#pragma unroll
        for (int r = 0; r < 4; ++r) {
#pragma unroll
            for (int msk = 1; msk < 16; msk <<= 1)
                pm[r] = fmaxf(pm[r], __shfl_xor(pm[r], msk));
        }
        f32x4 p0, p1;
        float rs[4];
#pragma unroll
        for (int r = 0; r < 4; ++r) {
            mn[r] = fmaxf(m_s[r], pm[r]);
            al[r] = __expf(m_s[r] - mn[r]);
            m_s[r] = mn[r];
            p0[r] = __expf(s[0][r] - mn[r]);
            p1[r] = __expf(s[1][r] - mn[r]);
            rs[r] = p0[r] + p1[r];
        }
#pragma unroll
        for (int r = 0; r < 4; ++r) {
#pragma unroll
            for (int msk = 1; msk < 16; msk <<= 1)
                rs[r] += __shfl_xor(rs[r], msk);
            l_s[r] = l_s[r] * al[r] + rs[r];
        }
#pragma unroll
        for (int nt = 0; nt < 4; ++nt)
#pragma unroll
            for (int r = 0; r < 4; ++r) o[nt][r] *= al[r];

        // P -> LDS (C/D layout: row=(lg)*4+r, col=ct*16+lq)
#pragma unroll
        for (int r = 0; r < 4; ++r) {
            plds[w][lg * 4 + r][lq]      = (__bf16)p0[r];
            plds[w][lg * 4 + r][16 + lq] = (__bf16)p1[r];
        }
        asm volatile("" ::: "memory");  // keep program order; same-wave DS is in-order
        // A-fragment of P: row=lq, k=lg*8+j
        bf16x8 pa = *(const bf16x8*)&plds[w][lq][lg * 8];
        // PV
#pragma unroll
        for (int nt = 0; nt < 4; ++nt) {
            bf16x8 bv = *(const bf16x8*)(vb + (size_t)(nt * 16 + lq) * T_ + s0 + lg * 8);
            o[nt] = __builtin_amdgcn_mfma_f32_16x16x32_bf16(pa, bv, o[nt], 0, 0, 0);
        }
    }

    // epilogue: out[b][t0+row][h] fp32, divide by row sum
    float* ob = out + ((size_t)b * T_ + t0) * HS_;
#pragma unroll
    for (int nt = 0; nt < 4; ++nt)
#pragma unroll
        for (int r = 0; r < 4; ++r)
            ob[(size_t)(lg * 4 + r) * HS_ + nt * 16 + lq] = o[nt][r] / l_s[r];
}

extern "C" void kernel_launch(void* const* d_in, const int* in_sizes, int n_in,
                              void* d_out, int out_size, void* d_ws, size_t ws_size,
                              hipStream_t stream) {
    const float* x  = (const float*)d_in[0];
    const float* Wq = (const float*)d_in[1];
    const float* Wk = (const float*)d_in[2];
    const float* Wv = (const float*)d_in[3];
    char* ws = (char*)d_ws;
    __bf16* wt = (__bf16*)ws;                     // 192*1024*2  = 393216 B
    __bf16* q  = (__bf16*)(ws + 393216);          // 8*2048*64*2 = 2097152 B
    __bf16* k  = (__bf16*)(ws + 2490368);
    __bf16* vt = (__bf16*)(ws + 4587520);
    float* out = (float*)d_out;

    wt_kernel<<<dim3(768), dim3(256), 0, stream>>>(Wq, Wk, Wv, wt);
    qkv_kernel<<<dim3(256), dim3(256), 0, stream>>>(x, wt, q, k, vt);
    attn_kernel<<<dim3(256), dim3(256), 0, stream>>>(q, k, vt, out);
}

// Round 2
// 137.081 us; speedup vs baseline: 1.0005x; 1.0005x over previous
//
#include <hip/hip_runtime.h>
#include <hip/hip_bf16.h>

#define B_ 8
#define T_ 2048
#define C_ 1024
#define HS_ 64

typedef float f32x4 __attribute__((ext_vector_type(4)));
typedef __bf16 bf16x8 __attribute__((ext_vector_type(8)));
typedef __bf16 bf16x4 __attribute__((ext_vector_type(4)));

// ---------------------------------------------------------------------------
// Kernel 1: transpose+scale weights into Wt[192][1024] bf16, coalesced via
// 64x64 LDS tile. Block b: matrix b>>4, k-tile (b&15)*64.
// Row n of wt: n<64 -> Wq col n (scaled 1/32); n<128 -> Wk; else Wv.
// ---------------------------------------------------------------------------
__global__ __launch_bounds__(256) void wt_kernel(const float* __restrict__ Wq,
                                                 const float* __restrict__ Wk,
                                                 const float* __restrict__ Wv,
                                                 __bf16* __restrict__ wt) {
    __shared__ float tile[64][65];
    int mb = blockIdx.x >> 4;          // matrix 0..2
    int k0 = (blockIdx.x & 15) * 64;   // k tile base
    const float* W = (mb == 0) ? Wq : (mb == 1 ? Wk : Wv);
    int c  = threadIdx.x & 63;
    int r0 = threadIdx.x >> 6;
#pragma unroll
    for (int r = r0; r < 64; r += 4)
        tile[r][c] = W[(size_t)(k0 + r) * 64 + c];
    __syncthreads();
    float scale = (mb == 0) ? 0.03125f : 1.0f;
    int kk = threadIdx.x & 63;
    int n0 = threadIdx.x >> 6;
#pragma unroll
    for (int n = n0; n < 64; n += 4)
        wt[(size_t)(mb * 64 + n) * C_ + k0 + kk] = (__bf16)(tile[kk][n] * scale);
}

// ---------------------------------------------------------------------------
// Kernel 2: QKV projection. 1024 blocks x 4 waves. Block owns 16 rows of x;
// each wave computes 3 of the 12 output col-tiles (full K). x loads are
// shared across waves via L1/L2.
// q,k stored [B*T][64] bf16; v stored transposed [B][64][T] bf16.
// ---------------------------------------------------------------------------
__global__ __launch_bounds__(256) void qkv_kernel(const float* __restrict__ x,
                                                  const __bf16* __restrict__ wt,
                                                  __bf16* __restrict__ q,
                                                  __bf16* __restrict__ k,
                                                  __bf16* __restrict__ vt) {
    int m0   = blockIdx.x * 16;
    int w    = threadIdx.x >> 6;
    int lane = threadIdx.x & 63;
    int lq = lane & 15;
    int lg = lane >> 4;

    f32x4 acc[3];
#pragma unroll
    for (int i = 0; i < 3; ++i) acc[i] = (f32x4)0.0f;

    const float* xrow = x + (size_t)(m0 + lq) * C_;
    for (int k0 = 0; k0 < C_; k0 += 32) {
        int kk = k0 + lg * 8;
        float4 x0 = *(const float4*)(xrow + kk);
        float4 x1 = *(const float4*)(xrow + kk + 4);
        bf16x8 a;
        a[0] = (__bf16)x0.x; a[1] = (__bf16)x0.y; a[2] = (__bf16)x0.z; a[3] = (__bf16)x0.w;
        a[4] = (__bf16)x1.x; a[5] = (__bf16)x1.y; a[6] = (__bf16)x1.z; a[7] = (__bf16)x1.w;
#pragma unroll
        for (int i = 0; i < 3; ++i) {
            int t = w * 3 + i;
            bf16x8 b = *(const bf16x8*)(wt + (size_t)(t * 16 + lq) * C_ + kk);
            acc[i] = __builtin_amdgcn_mfma_f32_16x16x32_bf16(a, b, acc[i], 0, 0, 0);
        }
    }

    int bb  = m0 >> 11;     // batch
    int tt0 = m0 & 2047;    // t within batch
#pragma unroll
    for (int i = 0; i < 3; ++i) {
        int t = w * 3 + i;
        if (t < 8) {
            __bf16* dst = (t < 4) ? q : k;
            int h = (t & 3) * 16 + lq;
#pragma unroll
            for (int r = 0; r < 4; ++r) {
                int row = m0 + lg * 4 + r;
                dst[(size_t)row * HS_ + h] = (__bf16)acc[i][r];
            }
        } else {
            int h = (t - 8) * 16 + lq;
            int trow = tt0 + lg * 4;
            bf16x4 pv;
#pragma unroll
            for (int r = 0; r < 4; ++r) pv[r] = (__bf16)acc[i][r];
            *(bf16x4*)(vt + ((size_t)bb * HS_ + h) * T_ + trow) = pv;
        }
    }
}

// ---------------------------------------------------------------------------
// Kernel 3: causal flash attention. One 512-thread block (8 waves) per
// 16-query tile; waves split key-tiles round-robin (kt = w, w+8, ...),
// each with private online-softmax state; flash-combine via LDS at the end.
// ---------------------------------------------------------------------------
__global__ __launch_bounds__(512) void attn_kernel(const __bf16* __restrict__ q,
                                                   const __bf16* __restrict__ k,
                                                   const __bf16* __restrict__ vt,
                                                   float* __restrict__ out) {
    __shared__ float olds[8][16][64];                      // 32 KB partial O
    __shared__ float mlds[8][16], llds[8][16];             // 1 KB m/l
    __shared__ __align__(16) __bf16 plds[8][16 * 40];      // 10 KB P staging

    int w    = threadIdx.x >> 6;
    int lane = threadIdx.x & 63;
    int lq = lane & 15;
    int lg = lane >> 4;

    int b  = blockIdx.x >> 7;          // batch
    int t0 = (blockIdx.x & 127) * 16;  // query block start

    const __bf16* qb = q  + ((size_t)b * T_ + t0) * HS_;
    const __bf16* kb = k  + (size_t)b * T_ * HS_;
    const __bf16* vb = vt + (size_t)b * HS_ * T_;

    // Q A-fragments (row = lane&15 -> query, k = (lane>>4)*8+j -> h)
    bf16x8 aq0 = *(const bf16x8*)(qb + (size_t)lq * HS_ + lg * 8);
    bf16x8 aq1 = *(const bf16x8*)(qb + (size_t)lq * HS_ + 32 + lg * 8);

    f32x4 o[4];
#pragma unroll
    for (int nt = 0; nt < 4; ++nt) o[nt] = (f32x4)0.0f;
    float m_s[4] = {-1e30f, -1e30f, -1e30f, -1e30f};
    float l_s[4] = {0.f, 0.f, 0.f, 0.f};

    __bf16* pw = &plds[w][0];

    int ntiles = (t0 + 47) >> 5;   // ceil((t0+16)/32)
    for (int kt = w; kt < ntiles; kt += 8) {
        int s0 = kt * 32;
        // S = Q K^T (scale pre-folded into Wq)
        f32x4 s[2];
#pragma unroll
        for (int ct = 0; ct < 2; ++ct) {
            const __bf16* kp = kb + (size_t)(s0 + ct * 16 + lq) * HS_;
            bf16x8 b0 = *(const bf16x8*)(kp + lg * 8);
            bf16x8 b1 = *(const bf16x8*)(kp + 32 + lg * 8);
            f32x4 a = (f32x4)0.0f;
            a = __builtin_amdgcn_mfma_f32_16x16x32_bf16(aq0, b0, a, 0, 0, 0);
            a = __builtin_amdgcn_mfma_f32_16x16x32_bf16(aq1, b1, a, 0, 0, 0);
            s[ct] = a;
        }
        // causal mask (tiles overlapping the diagonal only)
        if (s0 + 31 > t0) {
#pragma unroll
            for (int ct = 0; ct < 2; ++ct) {
                int scol = s0 + ct * 16 + lq;
#pragma unroll
                for (int r = 0; r < 4; ++r) {
                    int trow = t0 + lg * 4 + r;
                    if (scol > trow) s[ct][r] = -1e30f;
                }
            }
        }
        // online softmax
        float pm[4], mn[4], al[4];
#pragma unroll
        for (int r = 0; r < 4; ++r) pm[r] = fmaxf(s[0][r], s[1][r]);
#pragma unroll
        for (int r = 0; r < 4; ++r) {
#pragma unroll
            for (int msk = 1; msk < 16; msk <<= 1)
                pm[r] = fmaxf(pm[r], __shfl_xor(pm[r], msk));
        }
        f32x4 p0, p1;
        float rs[4];
#pragma unroll
        for (int r = 0; r < 4; ++r) {
            mn[r] = fmaxf(m_s[r], pm[r]);
            al[r] = __expf(m_s[r] - mn[r]);
            m_s[r] = mn[r];
            p0[r] = __expf(s[0][r] - mn[r]);
            p1[r] = __expf(s[1][r] - mn[r]);
            rs[r] = p0[r] + p1[r];
        }
#pragma unroll
        for (int r = 0; r < 4; ++r) {
#pragma unroll
            for (int msk = 1; msk < 16; msk <<= 1)
                rs[r] += __shfl_xor(rs[r], msk);
            l_s[r] = l_s[r] * al[r] + rs[r];
        }
#pragma unroll
        for (int nt = 0; nt < 4; ++nt)
#pragma unroll
            for (int r = 0; r < 4; ++r) o[nt][r] *= al[r];

        // P -> LDS (C/D layout: row=lg*4+r, col=ct*16+lq); stride 40 bf16
#pragma unroll
        for (int r = 0; r < 4; ++r) {
            pw[(lg * 4 + r) * 40 + lq]      = (__bf16)p0[r];
            pw[(lg * 4 + r) * 40 + 16 + lq] = (__bf16)p1[r];
        }
        asm volatile("" ::: "memory");
        // A-fragment of P: row=lq, k=lg*8+j
        bf16x8 pa = *(const bf16x8*)&pw[lq * 40 + lg * 8];
        // PV
#pragma unroll
        for (int nt = 0; nt < 4; ++nt) {
            bf16x8 bv = *(const bf16x8*)(vb + (size_t)(nt * 16 + lq) * T_ + s0 + lg * 8);
            o[nt] = __builtin_amdgcn_mfma_f32_16x16x32_bf16(pa, bv, o[nt], 0, 0, 0);
        }
    }

    // stash per-wave partials
    asm volatile("" ::: "memory");
#pragma unroll
    for (int nt = 0; nt < 4; ++nt)
#pragma unroll
        for (int r = 0; r < 4; ++r)
            olds[w][lg * 4 + r][nt * 16 + lq] = o[nt][r];
    if (lq == 0) {
#pragma unroll
        for (int r = 0; r < 4; ++r) {
            mlds[w][lg * 4 + r] = m_s[r];
            llds[w][lg * 4 + r] = l_s[r];
        }
    }
    __syncthreads();

    // flash-combine across 8 waves; 512 threads cover 16 rows x 32 col-pairs
    int row  = threadIdx.x >> 5;
    int col  = (threadIdx.x & 31) * 2;
    float M = -1e30f;
#pragma unroll
    for (int w2 = 0; w2 < 8; ++w2) M = fmaxf(M, mlds[w2][row]);
    float L = 0.f, o0 = 0.f, o1 = 0.f;
#pragma unroll
    for (int w2 = 0; w2 < 8; ++w2) {
        float sc = __expf(mlds[w2][row] - M);
        L  += sc * llds[w2][row];
        o0 += sc * olds[w2][row][col];
        o1 += sc * olds[w2][row][col + 1];
    }
    float inv = 1.0f / L;
    float* ob = out + ((size_t)b * T_ + t0 + row) * HS_ + col;
    ob[0] = o0 * inv;
    ob[1] = o1 * inv;
}

extern "C" void kernel_launch(void* const* d_in, const int* in_sizes, int n_in,
                              void* d_out, int out_size, void* d_ws, size_t ws_size,
                              hipStream_t stream) {
    const float* x  = (const float*)d_in[0];
    const float* Wq = (const float*)d_in[1];
    const float* Wk = (const float*)d_in[2];
    const float* Wv = (const float*)d_in[3];
    char* ws = (char*)d_ws;
    __bf16* wt = (__bf16*)ws;                     // 192*1024*2  = 393216 B
    __bf16* q  = (__bf16*)(ws + 393216);          // 8*2048*64*2 = 2097152 B
    __bf16* k  = (__bf16*)(ws + 2490368);
    __bf16* vt = (__bf16*)(ws + 4587520);
    float* out = (float*)d_out;

    wt_kernel<<<dim3(48), dim3(256), 0, stream>>>(Wq, Wk, Wv, wt);
    qkv_kernel<<<dim3(1024), dim3(256), 0, stream>>>(x, wt, q, k, vt);
    attn_kernel<<<dim3(1024), dim3(512), 0, stream>>>(q, k, vt, out);
}

// Round 3
// 125.602 us; speedup vs baseline: 1.0919x; 1.0914x over previous
//
#include <hip/hip_runtime.h>
#include <hip/hip_bf16.h>

#define B_ 8
#define T_ 2048
#define C_ 1024
#define HS_ 64

typedef float f32x4 __attribute__((ext_vector_type(4)));
typedef __bf16 bf16x8 __attribute__((ext_vector_type(8)));

// Fragment-layout workspaces:
//  Wf[12 nt][32 ks][64 lane][8]  : wt B-frags (q cols scaled by 1/32)
//  Qf[b*128+qt16][2 half][64][8] : Q A-frags
//  Kf[b*128+kt16][2 half][64][8] : K B-frags
//  Vf[b*64+kt32][4 ntv][64][8]   : V^T B-frags
// word (lane=lg*16+lq, j):
//  Wf = wt[nt*16+lq][ks*32+lg*8+j]
//  Qf = Q[qt*16+lq][half*32+lg*8+j]      Kf analogous
//  Vf = V[kt32*32+lg*8+j][ntv*16+lq]

// ---------------------------------------------------------------------------
// Kernel 1: weights -> Wf fragment layout (64x64 LDS transpose per block).
// ---------------------------------------------------------------------------
__global__ __launch_bounds__(256) void wt_kernel(const float* __restrict__ Wq,
                                                 const float* __restrict__ Wk,
                                                 const float* __restrict__ Wv,
                                                 __bf16* __restrict__ Wf) {
    __shared__ float tile[64][65];
    int mb = blockIdx.x >> 4;          // matrix 0..2
    int k0 = (blockIdx.x & 15) * 64;   // k tile base
    const float* W = (mb == 0) ? Wq : (mb == 1 ? Wk : Wv);
    int c = threadIdx.x & 63;
#pragma unroll
    for (int r = threadIdx.x >> 6; r < 64; r += 4)
        tile[r][c] = W[(size_t)(k0 + r) * 64 + c];
    __syncthreads();
    float scale = (mb == 0) ? 0.03125f : 1.0f;
    for (int u = threadIdx.x; u < 512; u += 256) {
        int ntl  = u >> 7;         // 0..3
        int ksl  = (u >> 6) & 1;   // 0..1
        int lane = u & 63;
        int lq = lane & 15, lg = lane >> 4;
        bf16x8 w8;
#pragma unroll
        for (int j = 0; j < 8; ++j)
            w8[j] = (__bf16)(tile[ksl * 32 + lg * 8 + j][ntl * 16 + lq] * scale);
        int ntg = mb * 4 + ntl;
        int ksg = (k0 >> 5) + ksl;
        *(bf16x8*)(Wf + (((size_t)ntg * 32 + ksg) * 64 + lane) * 8) = w8;
    }
}

// ---------------------------------------------------------------------------
// Kernel 2: QKV GEMM. 512 blocks x 4 waves. Block: 64 rows x 96 cols
// (n0 = 0 or 96). x staged in LDS (coalesced + reg prefetch); B-frags read
// directly from Wf. Epilogue re-layouts output into Qf/Kf/Vf via LDS.
// ---------------------------------------------------------------------------
__global__ __launch_bounds__(256) void qkv_kernel(const float* __restrict__ x,
                                                  const __bf16* __restrict__ Wf,
                                                  __bf16* __restrict__ qf,
                                                  __bf16* __restrict__ kf,
                                                  __bf16* __restrict__ vf) {
    __shared__ float xs[64][68];          // +4 pad: 2-way bank alias only
    __shared__ __bf16 obuf[64][104];      // epilogue staging (+8 pad)

    int m0 = (blockIdx.x >> 1) * 64;
    int n0 = (blockIdx.x & 1) * 96;
    int w    = threadIdx.x >> 6;
    int lane = threadIdx.x & 63;
    int lq = lane & 15, lg = lane >> 4;

    f32x4 acc[6];
#pragma unroll
    for (int i = 0; i < 6; ++i) acc[i] = (f32x4)0.0f;

    // prefetch k-tile 0
    float4 stg[4];
#pragma unroll
    for (int i = 0; i < 4; ++i) {
        int u = threadIdx.x + i * 256;
        stg[i] = *(const float4*)(x + (size_t)(m0 + (u >> 4)) * C_ + (u & 15) * 4);
    }

    for (int kt = 0; kt < 16; ++kt) {
        int k0 = kt * 64;
        __syncthreads();
#pragma unroll
        for (int i = 0; i < 4; ++i) {
            int u = threadIdx.x + i * 256;
            *(float4*)&xs[u >> 4][(u & 15) * 4] = stg[i];
        }
        __syncthreads();
        if (kt + 1 < 16) {
#pragma unroll
            for (int i = 0; i < 4; ++i) {
                int u = threadIdx.x + i * 256;
                stg[i] = *(const float4*)(x + (size_t)(m0 + (u >> 4)) * C_ + k0 + 64 + (u & 15) * 4);
            }
        }
#pragma unroll
        for (int ks = 0; ks < 2; ++ks) {
            const float* ar = &xs[w * 16 + lq][ks * 32 + lg * 8];
            float4 a0 = *(const float4*)ar;
            float4 a1 = *(const float4*)(ar + 4);
            bf16x8 a;
            a[0] = (__bf16)a0.x; a[1] = (__bf16)a0.y; a[2] = (__bf16)a0.z; a[3] = (__bf16)a0.w;
            a[4] = (__bf16)a1.x; a[5] = (__bf16)a1.y; a[6] = (__bf16)a1.z; a[7] = (__bf16)a1.w;
#pragma unroll
            for (int nt = 0; nt < 6; ++nt) {
                bf16x8 b = *(const bf16x8*)(Wf +
                    (((size_t)((n0 >> 4) + nt) * 32 + (k0 >> 5) + ks) * 64 + lane) * 8);
                acc[nt] = __builtin_amdgcn_mfma_f32_16x16x32_bf16(a, b, acc[nt], 0, 0, 0);
            }
        }
    }

    // epilogue: C/D layout (row=lg*4+r, col=lq) -> obuf -> fragment stores
    __syncthreads();
#pragma unroll
    for (int nt = 0; nt < 6; ++nt)
#pragma unroll
        for (int r = 0; r < 4; ++r)
            obuf[w * 16 + lg * 4 + r][nt * 16 + lq] = (__bf16)acc[nt][r];
    __syncthreads();

    size_t qt16 = (size_t)(m0 >> 4) + w;
    if (n0 == 0) {
        // cols 0-63 = q halves 0,1 ; cols 64-95 = k half 0
#pragma unroll
        for (int h = 0; h < 3; ++h) {
            bf16x8 v;
#pragma unroll
            for (int j = 0; j < 8; ++j)
                v[j] = obuf[w * 16 + lq][h * 32 + lg * 8 + j];
            __bf16* dst = (h < 2) ? (qf + ((qt16 * 2 + h) * 64 + lane) * 8)
                                  : (kf + ((qt16 * 2 + 0) * 64 + lane) * 8);
            *(bf16x8*)dst = v;
        }
    } else {
        // cols 0-31 = k half 1 ; cols 32-95 = v (h 0-63)
        bf16x8 v;
#pragma unroll
        for (int j = 0; j < 8; ++j)
            v[j] = obuf[w * 16 + lq][lg * 8 + j];
        *(bf16x8*)(kf + ((qt16 * 2 + 1) * 64 + lane) * 8) = v;
#pragma unroll
        for (int sub = 0; sub < 2; ++sub) {
            bf16x8 vv;
#pragma unroll
            for (int j = 0; j < 8; ++j)
                vv[j] = obuf[sub * 32 + lg * 8 + j][32 + w * 16 + lq];
            size_t kt32 = (size_t)(m0 >> 5) + sub;
            *(bf16x8*)(vf + ((kt32 * 4 + w) * 64 + lane) * 8) = vv;
        }
    }
}

// ---------------------------------------------------------------------------
// Kernel 3: causal flash attention. 8 waves/block per 16-query tile; waves
// split key-tiles round-robin; all operand loads are coalesced 16B/lane
// fragment loads from Qf/Kf/Vf; flash-combine across waves via LDS.
// ---------------------------------------------------------------------------
__global__ __launch_bounds__(512) void attn_kernel(const __bf16* __restrict__ qf,
                                                   const __bf16* __restrict__ kf,
                                                   const __bf16* __restrict__ vf,
                                                   float* __restrict__ out) {
    __shared__ float olds[8][16][64];
    __shared__ float mlds[8][16], llds[8][16];
    __shared__ __align__(16) __bf16 plds[8][16 * 40];

    int w    = threadIdx.x >> 6;
    int lane = threadIdx.x & 63;
    int lq = lane & 15, lg = lane >> 4;

    int b  = blockIdx.x >> 7;
    int t0 = (blockIdx.x & 127) * 16;

    // Q A-fragments
    size_t qbase = ((size_t)b * 128 + (t0 >> 4)) * 2;
    bf16x8 aq0 = *(const bf16x8*)(qf + ((qbase + 0) * 64 + lane) * 8);
    bf16x8 aq1 = *(const bf16x8*)(qf + ((qbase + 1) * 64 + lane) * 8);

    f32x4 o[4];
#pragma unroll
    for (int nt = 0; nt < 4; ++nt) o[nt] = (f32x4)0.0f;
    float m_s[4] = {-1e30f, -1e30f, -1e30f, -1e30f};
    float l_s[4] = {0.f, 0.f, 0.f, 0.f};

    __bf16* pw = &plds[w][0];

    int ntiles = (t0 + 47) >> 5;
    for (int kt = w; kt < ntiles; kt += 8) {
        int s0 = kt * 32;
        f32x4 s[2];
#pragma unroll
        for (int ct = 0; ct < 2; ++ct) {
            size_t kbase = ((size_t)b * 128 + (s0 >> 4) + ct) * 2;
            bf16x8 b0 = *(const bf16x8*)(kf + ((kbase + 0) * 64 + lane) * 8);
            bf16x8 b1 = *(const bf16x8*)(kf + ((kbase + 1) * 64 + lane) * 8);
            f32x4 a = (f32x4)0.0f;
            a = __builtin_amdgcn_mfma_f32_16x16x32_bf16(aq0, b0, a, 0, 0, 0);
            a = __builtin_amdgcn_mfma_f32_16x16x32_bf16(aq1, b1, a, 0, 0, 0);
            s[ct] = a;
        }
        if (s0 + 31 > t0) {
#pragma unroll
            for (int ct = 0; ct < 2; ++ct) {
                int scol = s0 + ct * 16 + lq;
#pragma unroll
                for (int r = 0; r < 4; ++r) {
                    int trow = t0 + lg * 4 + r;
                    if (scol > trow) s[ct][r] = -1e30f;
                }
            }
        }
        float pm[4], mn[4], al[4];
#pragma unroll
        for (int r = 0; r < 4; ++r) pm[r] = fmaxf(s[0][r], s[1][r]);
#pragma unroll
        for (int r = 0; r < 4; ++r) {
#pragma unroll
            for (int msk = 1; msk < 16; msk <<= 1)
                pm[r] = fmaxf(pm[r], __shfl_xor(pm[r], msk));
        }
        f32x4 p0, p1;
        float rs[4];
#pragma unroll
        for (int r = 0; r < 4; ++r) {
            mn[r] = fmaxf(m_s[r], pm[r]);
            al[r] = __expf(m_s[r] - mn[r]);
            m_s[r] = mn[r];
            p0[r] = __expf(s[0][r] - mn[r]);
            p1[r] = __expf(s[1][r] - mn[r]);
            rs[r] = p0[r] + p1[r];
        }
#pragma unroll
        for (int r = 0; r < 4; ++r) {
#pragma unroll
            for (int msk = 1; msk < 16; msk <<= 1)
                rs[r] += __shfl_xor(rs[r], msk);
            l_s[r] = l_s[r] * al[r] + rs[r];
        }
#pragma unroll
        for (int nt = 0; nt < 4; ++nt)
#pragma unroll
            for (int r = 0; r < 4; ++r) o[nt][r] *= al[r];

#pragma unroll
        for (int r = 0; r < 4; ++r) {
            pw[(lg * 4 + r) * 40 + lq]      = (__bf16)p0[r];
            pw[(lg * 4 + r) * 40 + 16 + lq] = (__bf16)p1[r];
        }
        asm volatile("" ::: "memory");
        bf16x8 pa = *(const bf16x8*)&pw[lq * 40 + lg * 8];
#pragma unroll
        for (int nt = 0; nt < 4; ++nt) {
            bf16x8 bv = *(const bf16x8*)(vf +
                (((size_t)(b * 64 + (s0 >> 5)) * 4 + nt) * 64 + lane) * 8);
            o[nt] = __builtin_amdgcn_mfma_f32_16x16x32_bf16(pa, bv, o[nt], 0, 0, 0);
        }
    }

    asm volatile("" ::: "memory");
#pragma unroll
    for (int nt = 0; nt < 4; ++nt)
#pragma unroll
        for (int r = 0; r < 4; ++r)
            olds[w][lg * 4 + r][nt * 16 + lq] = o[nt][r];
    if (lq == 0) {
#pragma unroll
        for (int r = 0; r < 4; ++r) {
            mlds[w][lg * 4 + r] = m_s[r];
            llds[w][lg * 4 + r] = l_s[r];
        }
    }
    __syncthreads();

    int row = threadIdx.x >> 5;
    int col = (threadIdx.x & 31) * 2;
    float M = -1e30f;
#pragma unroll
    for (int w2 = 0; w2 < 8; ++w2) M = fmaxf(M, mlds[w2][row]);
    float L = 0.f, o0 = 0.f, o1 = 0.f;
#pragma unroll
    for (int w2 = 0; w2 < 8; ++w2) {
        float sc = __expf(mlds[w2][row] - M);
        L  += sc * llds[w2][row];
        o0 += sc * olds[w2][row][col];
        o1 += sc * olds[w2][row][col + 1];
    }
    float inv = 1.0f / L;
    float* ob = out + ((size_t)b * T_ + t0 + row) * HS_ + col;
    ob[0] = o0 * inv;
    ob[1] = o1 * inv;
}

extern "C" void kernel_launch(void* const* d_in, const int* in_sizes, int n_in,
                              void* d_out, int out_size, void* d_ws, size_t ws_size,
                              hipStream_t stream) {
    const float* x  = (const float*)d_in[0];
    const float* Wq = (const float*)d_in[1];
    const float* Wk = (const float*)d_in[2];
    const float* Wv = (const float*)d_in[3];
    char* ws = (char*)d_ws;
    __bf16* Wf = (__bf16*)ws;                     // 393216 B
    __bf16* qf = (__bf16*)(ws + 393216);          // 2 MB
    __bf16* kf = (__bf16*)(ws + 2490368);         // 2 MB
    __bf16* vf = (__bf16*)(ws + 4587520);         // 2 MB
    float* out = (float*)d_out;

    wt_kernel<<<dim3(48), dim3(256), 0, stream>>>(Wq, Wk, Wv, Wf);
    qkv_kernel<<<dim3(512), dim3(256), 0, stream>>>(x, Wf, qf, kf, vf);
    attn_kernel<<<dim3(1024), dim3(512), 0, stream>>>(qf, kf, vf, out);
}

// Round 4
// 55.319 us; speedup vs baseline: 2.4791x; 2.2705x over previous
//
#include <hip/hip_runtime.h>
#include <hip/hip_bf16.h>

#define B_ 8
#define T_ 2048
#define C_ 1024
#define HS_ 64

typedef float f32x4 __attribute__((ext_vector_type(4)));
typedef __bf16 bf16x8 __attribute__((ext_vector_type(8)));

// Workspaces:
//  wt[192][1024] bf16 linear: rows 0-63 Wq^T cols (scaled 1/32), 64-127 Wk^T, 128-191 Wv^T
//  Qf[b*128+qt16][2 half][64 lane][8] : Q A-frags   (word = Q[qt*16+lq][half*32+lg*8+j])
//  Kf same ; Vf[b*64+kt32][4 ntv][64][8] (word = V[kt32*32+lg*8+j][ntv*16+lq])

// ---------------------------------------------------------------------------
// Kernel 1: W [1024][64] fp32 -> wt [192][1024] bf16 (transposed, q scaled).
// ---------------------------------------------------------------------------
__global__ __launch_bounds__(256) void wt_kernel(const float* __restrict__ Wq,
                                                 const float* __restrict__ Wk,
                                                 const float* __restrict__ Wv,
                                                 __bf16* __restrict__ wt) {
    __shared__ float tile[64][65];
    int mb = blockIdx.x >> 4;          // matrix 0..2
    int k0 = (blockIdx.x & 15) * 64;   // k tile base
    const float* W = (mb == 0) ? Wq : (mb == 1 ? Wk : Wv);
    int c = threadIdx.x & 63;
#pragma unroll
    for (int r = threadIdx.x >> 6; r < 64; r += 4)
        tile[r][c] = W[(size_t)(k0 + r) * 64 + c];
    __syncthreads();
    float scale = (mb == 0) ? 0.03125f : 1.0f;
    int kk = threadIdx.x & 63;
#pragma unroll
    for (int n = threadIdx.x >> 6; n < 64; n += 4)
        wt[(size_t)(mb * 64 + n) * C_ + k0 + kk] = (__bf16)(tile[kk][n] * scale);
}

// ---------------------------------------------------------------------------
// Kernel 2: QKV GEMM, LDS-staged both operands, double-buffered.
// 256 blocks x 512 thr (8 waves). Block: 64 rows x 192 cols, K-step 64.
// LDS: xs[2] 8KB bf16 (x slice) + ws[2] 24KB bf16 (W slice), XOR-swizzled
// 16B chunks (chunk ^= row&7) -> conflict-free ds_read_b128 fragments.
// Wave w: m-tiles {(w&1)*2,+1} x nt {(w>>1)*3..+2}. Epilogue -> Qf/Kf/Vf.
// ---------------------------------------------------------------------------
__global__ __launch_bounds__(512) void qkv_kernel(const float* __restrict__ x,
                                                  const __bf16* __restrict__ wt,
                                                  __bf16* __restrict__ qf,
                                                  __bf16* __restrict__ kf,
                                                  __bf16* __restrict__ vf) {
    __shared__ __align__(16) char smem[65536];
    __bf16* xs0 = (__bf16*)smem;               // [64][64] swz, 8KB
    __bf16* xs1 = (__bf16*)(smem + 8192);
    __bf16* ws0 = (__bf16*)(smem + 16384);     // [192][64] swz, 24KB
    __bf16* ws1 = (__bf16*)(smem + 40960);

    const int tid = threadIdx.x;
    const int w = tid >> 6, lane = tid & 63, lq = lane & 15, lg = lane >> 4;
    const int m0 = blockIdx.x * 64;
    const int mtb = (w & 1) * 2;          // first of 2 m-tiles
    const int ntb = (w >> 1) * 3;         // first of 3 nt-tiles

    f32x4 acc[2][3];
#pragma unroll
    for (int mi = 0; mi < 2; ++mi)
#pragma unroll
        for (int i = 0; i < 3; ++i) acc[mi][i] = (f32x4)0.0f;

    // stage-reg slots: x: tid -> row=tid>>3 (0..63), ch=tid&7 (32B fp32 src)
    //                  w: u=tid+s*512 -> row=u>>3 (0..191), ch=u&7 (16B src)
    const int xrow = tid >> 3, xch = tid & 7;
    float4 xr0, xr1;
    bf16x8 wr[3];

    // prologue: load kt=0, write buf0
    {
        const float* xp = x + (size_t)(m0 + xrow) * C_ + xch * 8;
        xr0 = *(const float4*)xp;
        xr1 = *(const float4*)(xp + 4);
#pragma unroll
        for (int s = 0; s < 3; ++s) {
            int u = tid + s * 512;
            wr[s] = *(const bf16x8*)(wt + (size_t)(u >> 3) * C_ + (u & 7) * 8);
        }
        bf16x8 xb;
#pragma unroll
        for (int j = 0; j < 4; ++j) { xb[j] = (__bf16)xr0[j]; xb[4 + j] = (__bf16)xr1[j]; }
        *(bf16x8*)(xs0 + xrow * 64 + ((xch ^ (xrow & 7)) * 8)) = xb;
#pragma unroll
        for (int s = 0; s < 3; ++s) {
            int u = tid + s * 512, rw = u >> 3, ch = u & 7;
            *(bf16x8*)(ws0 + rw * 64 + ((ch ^ (rw & 7)) * 8)) = wr[s];
        }
    }

    for (int kt = 0; kt < 16; ++kt) {
        __syncthreads();
        __bf16* xsc = (kt & 1) ? xs1 : xs0;
        __bf16* wsc = (kt & 1) ? ws1 : ws0;
        // issue next-tile global loads early (hide under compute)
        if (kt < 15) {
            int k0 = (kt + 1) * 64;
            const float* xp = x + (size_t)(m0 + xrow) * C_ + k0 + xch * 8;
            xr0 = *(const float4*)xp;
            xr1 = *(const float4*)(xp + 4);
#pragma unroll
            for (int s = 0; s < 3; ++s) {
                int u = tid + s * 512;
                wr[s] = *(const bf16x8*)(wt + (size_t)(u >> 3) * C_ + k0 + (u & 7) * 8);
            }
        }
        // compute current buffer
#pragma unroll
        for (int ks = 0; ks < 2; ++ks) {
            bf16x8 a[2];
#pragma unroll
            for (int mi = 0; mi < 2; ++mi) {
                int r = (mtb + mi) * 16 + lq;
                a[mi] = *(const bf16x8*)(xsc + r * 64 + (((ks * 4 + lg) ^ (r & 7)) * 8));
            }
#pragma unroll
            for (int i = 0; i < 3; ++i) {
                int rw = (ntb + i) * 16 + lq;
                bf16x8 b = *(const bf16x8*)(wsc + rw * 64 + (((ks * 4 + lg) ^ (rw & 7)) * 8));
#pragma unroll
                for (int mi = 0; mi < 2; ++mi)
                    acc[mi][i] = __builtin_amdgcn_mfma_f32_16x16x32_bf16(a[mi], b, acc[mi][i], 0, 0, 0);
            }
        }
        // write next buffer
        if (kt < 15) {
            __bf16* xsn = (kt & 1) ? xs0 : xs1;
            __bf16* wsn = (kt & 1) ? ws0 : ws1;
            bf16x8 xb;
#pragma unroll
            for (int j = 0; j < 4; ++j) { xb[j] = (__bf16)xr0[j]; xb[4 + j] = (__bf16)xr1[j]; }
            *(bf16x8*)(xsn + xrow * 64 + ((xch ^ (xrow & 7)) * 8)) = xb;
#pragma unroll
            for (int s = 0; s < 3; ++s) {
                int u = tid + s * 512, rw = u >> 3, ch = u & 7;
                *(bf16x8*)(wsn + rw * 64 + ((ch ^ (rw & 7)) * 8)) = wr[s];
            }
        }
    }
    __syncthreads();

    // epilogue: acc -> obuf [64][208] bf16 (overlay on smem) -> fragment stores
    __bf16(*obuf)[208] = (__bf16(*)[208])smem;
#pragma unroll
    for (int mi = 0; mi < 2; ++mi)
#pragma unroll
        for (int i = 0; i < 3; ++i)
#pragma unroll
            for (int r = 0; r < 4; ++r)
                obuf[(mtb + mi) * 16 + lg * 4 + r][(ntb + i) * 16 + lq] = (__bf16)acc[mi][i][r];
    __syncthreads();

    // Qf / Kf: wave w -> m-subtile w>>1, half w&1
    {
        int mg = w >> 1, half = w & 1;
        size_t qt16 = (size_t)(m0 >> 4) + mg;
        bf16x8 vq = *(const bf16x8*)&obuf[mg * 16 + lq][half * 32 + lg * 8];
        bf16x8 vk = *(const bf16x8*)&obuf[mg * 16 + lq][64 + half * 32 + lg * 8];
        *(bf16x8*)(qf + ((qt16 * 2 + half) * 64 + lane) * 8) = vq;
        *(bf16x8*)(kf + ((qt16 * 2 + half) * 64 + lane) * 8) = vk;
    }
    // Vf: wave w -> kt32 sub w>>2, ntv w&3
    {
        int kl = w >> 2, ntv = w & 3;
        bf16x8 vv;
#pragma unroll
        for (int j = 0; j < 8; ++j)
            vv[j] = obuf[kl * 32 + lg * 8 + j][128 + ntv * 16 + lq];
        size_t kt32 = (size_t)(m0 >> 5) + kl;
        *(bf16x8*)(vf + ((kt32 * 4 + ntv) * 64 + lane) * 8) = vv;
    }
}

// ---------------------------------------------------------------------------
// Kernel 3: causal flash attention (unchanged from round 2/3 — passes,
// ~16us). 8 waves/block per 16-query tile; waves split key-tiles
// round-robin; coalesced fragment loads; flash-combine via LDS.
// ---------------------------------------------------------------------------
__global__ __launch_bounds__(512) void attn_kernel(const __bf16* __restrict__ qf,
                                                   const __bf16* __restrict__ kf,
                                                   const __bf16* __restrict__ vf,
                                                   float* __restrict__ out) {
    __shared__ float olds[8][16][64];
    __shared__ float mlds[8][16], llds[8][16];
    __shared__ __align__(16) __bf16 plds[8][16 * 40];

    int w    = threadIdx.x >> 6;
    int lane = threadIdx.x & 63;
    int lq = lane & 15, lg = lane >> 4;

    int b  = blockIdx.x >> 7;
    int t0 = (blockIdx.x & 127) * 16;

    size_t qbase = ((size_t)b * 128 + (t0 >> 4)) * 2;
    bf16x8 aq0 = *(const bf16x8*)(qf + ((qbase + 0) * 64 + lane) * 8);
    bf16x8 aq1 = *(const bf16x8*)(qf + ((qbase + 1) * 64 + lane) * 8);

    f32x4 o[4];
#pragma unroll
    for (int nt = 0; nt < 4; ++nt) o[nt] = (f32x4)0.0f;
    float m_s[4] = {-1e30f, -1e30f, -1e30f, -1e30f};
    float l_s[4] = {0.f, 0.f, 0.f, 0.f};

    __bf16* pw = &plds[w][0];

    int ntiles = (t0 + 47) >> 5;
    for (int kt = w; kt < ntiles; kt += 8) {
        int s0 = kt * 32;
        f32x4 s[2];
#pragma unroll
        for (int ct = 0; ct < 2; ++ct) {
            size_t kbase = ((size_t)b * 128 + (s0 >> 4) + ct) * 2;
            bf16x8 b0 = *(const bf16x8*)(kf + ((kbase + 0) * 64 + lane) * 8);
            bf16x8 b1 = *(const bf16x8*)(kf + ((kbase + 1) * 64 + lane) * 8);
            f32x4 a = (f32x4)0.0f;
            a = __builtin_amdgcn_mfma_f32_16x16x32_bf16(aq0, b0, a, 0, 0, 0);
            a = __builtin_amdgcn_mfma_f32_16x16x32_bf16(aq1, b1, a, 0, 0, 0);
            s[ct] = a;
        }
        if (s0 + 31 > t0) {
#pragma unroll
            for (int ct = 0; ct < 2; ++ct) {
                int scol = s0 + ct * 16 + lq;
#pragma unroll
                for (int r = 0; r < 4; ++r) {
                    int trow = t0 + lg * 4 + r;
                    if (scol > trow) s[ct][r] = -1e30f;
                }
            }
        }
        float pm[4], mn[4], al[4];
#pragma unroll
        for (int r = 0; r < 4; ++r) pm[r] = fmaxf(s[0][r], s[1][r]);
#pragma unroll
        for (int r = 0; r < 4; ++r) {
#pragma unroll
            for (int msk = 1; msk < 16; msk <<= 1)
                pm[r] = fmaxf(pm[r], __shfl_xor(pm[r], msk));
        }
        f32x4 p0, p1;
        float rs[4];
#pragma unroll
        for (int r = 0; r < 4; ++r) {
            mn[r] = fmaxf(m_s[r], pm[r]);
            al[r] = __expf(m_s[r] - mn[r]);
            m_s[r] = mn[r];
            p0[r] = __expf(s[0][r] - mn[r]);
            p1[r] = __expf(s[1][r] - mn[r]);
            rs[r] = p0[r] + p1[r];
        }
#pragma unroll
        for (int r = 0; r < 4; ++r) {
#pragma unroll
            for (int msk = 1; msk < 16; msk <<= 1)
                rs[r] += __shfl_xor(rs[r], msk);
            l_s[r] = l_s[r] * al[r] + rs[r];
        }
#pragma unroll
        for (int nt = 0; nt < 4; ++nt)
#pragma unroll
            for (int r = 0; r < 4; ++r) o[nt][r] *= al[r];

#pragma unroll
        for (int r = 0; r < 4; ++r) {
            pw[(lg * 4 + r) * 40 + lq]      = (__bf16)p0[r];
            pw[(lg * 4 + r) * 40 + 16 + lq] = (__bf16)p1[r];
        }
        asm volatile("" ::: "memory");
        bf16x8 pa = *(const bf16x8*)&pw[lq * 40 + lg * 8];
#pragma unroll
        for (int nt = 0; nt < 4; ++nt) {
            bf16x8 bv = *(const bf16x8*)(vf +
                (((size_t)(b * 64 + (s0 >> 5)) * 4 + nt) * 64 + lane) * 8);
            o[nt] = __builtin_amdgcn_mfma_f32_16x16x32_bf16(pa, bv, o[nt], 0, 0, 0);
        }
    }

    asm volatile("" ::: "memory");
#pragma unroll
    for (int nt = 0; nt < 4; ++nt)
#pragma unroll
        for (int r = 0; r < 4; ++r)
            olds[w][lg * 4 + r][nt * 16 + lq] = o[nt][r];
    if (lq == 0) {
#pragma unroll
        for (int r = 0; r < 4; ++r) {
            mlds[w][lg * 4 + r] = m_s[r];
            llds[w][lg * 4 + r] = l_s[r];
        }
    }
    __syncthreads();

    int row = threadIdx.x >> 5;
    int col = (threadIdx.x & 31) * 2;
    float M = -1e30f;
#pragma unroll
    for (int w2 = 0; w2 < 8; ++w2) M = fmaxf(M, mlds[w2][row]);
    float L = 0.f, o0 = 0.f, o1 = 0.f;
#pragma unroll
    for (int w2 = 0; w2 < 8; ++w2) {
        float sc = __expf(mlds[w2][row] - M);
        L  += sc * llds[w2][row];
        o0 += sc * olds[w2][row][col];
        o1 += sc * olds[w2][row][col + 1];
    }
    float inv = 1.0f / L;
    float* ob = out + ((size_t)b * T_ + t0 + row) * HS_ + col;
    ob[0] = o0 * inv;
    ob[1] = o1 * inv;
}

extern "C" void kernel_launch(void* const* d_in, const int* in_sizes, int n_in,
                              void* d_out, int out_size, void* d_ws, size_t ws_size,
                              hipStream_t stream) {
    const float* x  = (const float*)d_in[0];
    const float* Wq = (const float*)d_in[1];
    const float* Wk = (const float*)d_in[2];
    const float* Wv = (const float*)d_in[3];
    char* ws = (char*)d_ws;
    __bf16* wt = (__bf16*)ws;                     // 393216 B
    __bf16* qf = (__bf16*)(ws + 393216);          // 2 MB
    __bf16* kf = (__bf16*)(ws + 2490368);         // 2 MB
    __bf16* vf = (__bf16*)(ws + 4587520);         // 2 MB
    float* out = (float*)d_out;

    wt_kernel<<<dim3(48), dim3(256), 0, stream>>>(Wq, Wk, Wv, wt);
    qkv_kernel<<<dim3(256), dim3(512), 0, stream>>>(x, wt, qf, kf, vf);
    attn_kernel<<<dim3(1024), dim3(512), 0, stream>>>(qf, kf, vf, out);
}

// Round 5
// 41.064 us; speedup vs baseline: 3.3398x; 1.3472x over previous
//
#include <hip/hip_runtime.h>
#include <hip/hip_bf16.h>

#define B_ 8
#define T_ 2048
#define C_ 1024
#define HS_ 64

typedef float f32x4 __attribute__((ext_vector_type(4)));
typedef __bf16 bf16x8 __attribute__((ext_vector_type(8)));
typedef __bf16 bf16x4 __attribute__((ext_vector_type(4)));

// Workspaces:
//  wt[192][1024] bf16: rows 0-63 Wq^T (scaled 1/32), 64-127 Wk^T, 128-191 Wv^T
//  Qf[b*128+qt16][2 half][64 lane][8] : word = Q[qt*16+(lane&15)][half*32+(lane>>4)*8+j]
//  Kf identical mapping for K.  (A-frag and B-frag word layouts coincide.)
//  Vf[b*64+kt32][4 ntv][64][8] : word = V[kt32*32+(lane>>4)*8+j][ntv*16+(lane&15)]

// ---------------------------------------------------------------------------
// Kernel 1: W [1024][64] fp32 -> wt [192][1024] bf16 (transposed, q scaled).
// ---------------------------------------------------------------------------
__global__ __launch_bounds__(256) void wt_kernel(const float* __restrict__ Wq,
                                                 const float* __restrict__ Wk,
                                                 const float* __restrict__ Wv,
                                                 __bf16* __restrict__ wt) {
    __shared__ float tile[64][65];
    int mb = blockIdx.x >> 4;          // matrix 0..2
    int k0 = (blockIdx.x & 15) * 64;   // k tile base
    const float* W = (mb == 0) ? Wq : (mb == 1 ? Wk : Wv);
    int c = threadIdx.x & 63;
#pragma unroll
    for (int r = threadIdx.x >> 6; r < 64; r += 4)
        tile[r][c] = W[(size_t)(k0 + r) * 64 + c];
    __syncthreads();
    float scale = (mb == 0) ? 0.03125f : 1.0f;
    int kk = threadIdx.x & 63;
#pragma unroll
    for (int n = threadIdx.x >> 6; n < 64; n += 4)
        wt[(size_t)(mb * 64 + n) * C_ + k0 + kk] = (__bf16)(tile[kk][n] * scale);
}

// ---------------------------------------------------------------------------
// Kernel 2: QKV GEMM. 512 blocks x 512 thr (8 waves), 2 blocks/CU.
// Block: 32 rows x 192 cols, K-step 64, dual swizzled LDS staging (56KB).
// Wave w: m-tile w&1, nt tiles (w>>1)*3..+2. Epilogue -> Qf/Kf/Vf.
// ---------------------------------------------------------------------------
__global__ __launch_bounds__(512) void qkv_kernel(const float* __restrict__ x,
                                                  const __bf16* __restrict__ wt,
                                                  __bf16* __restrict__ qf,
                                                  __bf16* __restrict__ kf,
                                                  __bf16* __restrict__ vf) {
    __shared__ __align__(16) char smem[57344];
    __bf16* xs0 = (__bf16*)smem;               // [32][64] swz, 4KB
    __bf16* xs1 = (__bf16*)(smem + 4096);
    __bf16* ws0 = (__bf16*)(smem + 8192);      // [192][64] swz, 24KB
    __bf16* ws1 = (__bf16*)(smem + 32768);

    const int tid = threadIdx.x;
    const int w = tid >> 6, lane = tid & 63, lq = lane & 15, lg = lane >> 4;
    const int m0 = blockIdx.x * 32;
    const int mt = w & 1;
    const int ntb = (w >> 1) * 3;

    f32x4 acc[3];
#pragma unroll
    for (int i = 0; i < 3; ++i) acc[i] = (f32x4)0.0f;

    const int xrow = tid >> 3, xch = tid & 7;   // x slots: tid<256
    float4 xr0, xr1;
    bf16x8 wr[3];

    // prologue: load kt=0 and fill buf0
    if (tid < 256) {
        const float* xp = x + (size_t)(m0 + xrow) * C_ + xch * 8;
        xr0 = *(const float4*)xp;
        xr1 = *(const float4*)(xp + 4);
    }
#pragma unroll
    for (int s = 0; s < 3; ++s) {
        int u = tid + s * 512;
        wr[s] = *(const bf16x8*)(wt + (size_t)(u >> 3) * C_ + (u & 7) * 8);
    }
    if (tid < 256) {
        bf16x8 xb;
#pragma unroll
        for (int j = 0; j < 4; ++j) { xb[j] = (__bf16)xr0[j]; xb[4 + j] = (__bf16)xr1[j]; }
        *(bf16x8*)(xs0 + xrow * 64 + ((xch ^ (xrow & 7)) * 8)) = xb;
    }
#pragma unroll
    for (int s = 0; s < 3; ++s) {
        int u = tid + s * 512, rw = u >> 3, ch = u & 7;
        *(bf16x8*)(ws0 + rw * 64 + ((ch ^ (rw & 7)) * 8)) = wr[s];
    }

    for (int kt = 0; kt < 16; ++kt) {
        __syncthreads();
        __bf16* xsc = (kt & 1) ? xs1 : xs0;
        __bf16* wsc = (kt & 1) ? ws1 : ws0;
        if (kt < 15) {
            int k0 = (kt + 1) * 64;
            if (tid < 256) {
                const float* xp = x + (size_t)(m0 + xrow) * C_ + k0 + xch * 8;
                xr0 = *(const float4*)xp;
                xr1 = *(const float4*)(xp + 4);
            }
#pragma unroll
            for (int s = 0; s < 3; ++s) {
                int u = tid + s * 512;
                wr[s] = *(const bf16x8*)(wt + (size_t)(u >> 3) * C_ + k0 + (u & 7) * 8);
            }
        }
#pragma unroll
        for (int ks = 0; ks < 2; ++ks) {
            int r = mt * 16 + lq;
            bf16x8 a = *(const bf16x8*)(xsc + r * 64 + (((ks * 4 + lg) ^ (r & 7)) * 8));
#pragma unroll
            for (int i = 0; i < 3; ++i) {
                int rw = (ntb + i) * 16 + lq;
                bf16x8 b = *(const bf16x8*)(wsc + rw * 64 + (((ks * 4 + lg) ^ (rw & 7)) * 8));
                acc[i] = __builtin_amdgcn_mfma_f32_16x16x32_bf16(a, b, acc[i], 0, 0, 0);
            }
        }
        if (kt < 15) {
            __bf16* xsn = (kt & 1) ? xs0 : xs1;
            __bf16* wsn = (kt & 1) ? ws0 : ws1;
            if (tid < 256) {
                bf16x8 xb;
#pragma unroll
                for (int j = 0; j < 4; ++j) { xb[j] = (__bf16)xr0[j]; xb[4 + j] = (__bf16)xr1[j]; }
                *(bf16x8*)(xsn + xrow * 64 + ((xch ^ (xrow & 7)) * 8)) = xb;
            }
#pragma unroll
            for (int s = 0; s < 3; ++s) {
                int u = tid + s * 512, rw = u >> 3, ch = u & 7;
                *(bf16x8*)(wsn + rw * 64 + ((ch ^ (rw & 7)) * 8)) = wr[s];
            }
        }
    }
    __syncthreads();

    // epilogue: acc -> obuf [32][208] -> fragment stores
    __bf16(*obuf)[208] = (__bf16(*)[208])smem;
#pragma unroll
    for (int i = 0; i < 3; ++i)
#pragma unroll
        for (int r = 0; r < 4; ++r)
            obuf[mt * 16 + lg * 4 + r][(ntb + i) * 16 + lq] = (__bf16)acc[i][r];
    __syncthreads();

    if (w < 4) {
        int mg = w & 1, half = w >> 1;
        size_t qt16 = (size_t)(m0 >> 4) + mg;
        bf16x8 vq = *(const bf16x8*)&obuf[mg * 16 + lq][half * 32 + lg * 8];
        bf16x8 vk = *(const bf16x8*)&obuf[mg * 16 + lq][64 + half * 32 + lg * 8];
        *(bf16x8*)(qf + ((qt16 * 2 + half) * 64 + lane) * 8) = vq;
        *(bf16x8*)(kf + ((qt16 * 2 + half) * 64 + lane) * 8) = vk;
    } else {
        int ntv = w - 4;
        bf16x8 vv;
#pragma unroll
        for (int j = 0; j < 8; ++j)
            vv[j] = obuf[lg * 8 + j][128 + ntv * 16 + lq];
        size_t kt32 = (size_t)(m0 >> 5);
        *(bf16x8*)(vf + ((kt32 * 4 + ntv) * 64 + lane) * 8) = vv;
    }
}

// ---------------------------------------------------------------------------
// Kernel 3: causal flash attention, SWAPPED QK^T (S^T = K Q^T) so each
// lane's query is lane&15 and its 8 key-scores are in-register: softmax
// reduce = 7 in-reg ops + 2 shfl_xor. 8 waves/block split key-tiles
// round-robin; flash-combine via LDS. b = blockIdx&7 for XCD L2 affinity.
// ---------------------------------------------------------------------------
__global__ __launch_bounds__(512) void attn_kernel(const __bf16* __restrict__ qf,
                                                   const __bf16* __restrict__ kf,
                                                   const __bf16* __restrict__ vf,
                                                   float* __restrict__ out) {
    __shared__ float olds[8][16][64];
    __shared__ float mlds[8][16], llds[8][16];
    __shared__ __align__(16) __bf16 plds[8][16 * 40];

    int w    = threadIdx.x >> 6;
    int lane = threadIdx.x & 63;
    int lq = lane & 15, lg = lane >> 4;

    int b  = blockIdx.x & 7;
    int t0 = (blockIdx.x >> 3) * 16;

    size_t qbase = ((size_t)b * 128 + (t0 >> 4)) * 2;
    bf16x8 aq0 = *(const bf16x8*)(qf + ((qbase + 0) * 64 + lane) * 8);
    bf16x8 aq1 = *(const bf16x8*)(qf + ((qbase + 1) * 64 + lane) * 8);

    f32x4 o[4];
#pragma unroll
    for (int nt = 0; nt < 4; ++nt) o[nt] = (f32x4)0.0f;
    float m_s = -1e30f, l_s = 0.f;

    __bf16* pw = &plds[w][0];

    int ntiles = (t0 + 47) >> 5;
    for (int kt = w; kt < ntiles; kt += 8) {
        int s0 = kt * 32;
        // S^T tile: A = K frags, B = Q frags. col=lane&15=query, row=key
        f32x4 s[2];
#pragma unroll
        for (int ct = 0; ct < 2; ++ct) {
            size_t kbase = ((size_t)b * 128 + (s0 >> 4) + ct) * 2;
            bf16x8 k0 = *(const bf16x8*)(kf + ((kbase + 0) * 64 + lane) * 8);
            bf16x8 k1 = *(const bf16x8*)(kf + ((kbase + 1) * 64 + lane) * 8);
            f32x4 a = (f32x4)0.0f;
            a = __builtin_amdgcn_mfma_f32_16x16x32_bf16(k0, aq0, a, 0, 0, 0);
            a = __builtin_amdgcn_mfma_f32_16x16x32_bf16(k1, aq1, a, 0, 0, 0);
            s[ct] = a;
        }
        // causal mask: key = s0+ct*16+lg*4+r, query = t0+lq
        if (s0 + 31 > t0) {
#pragma unroll
            for (int ct = 0; ct < 2; ++ct)
#pragma unroll
                for (int r = 0; r < 4; ++r)
                    if (s0 + ct * 16 + lg * 4 + r > t0 + lq) s[ct][r] = -1e30f;
        }
        // per-lane softmax for query lq: 8 in-reg scores + lg-group combine
        float pm = fmaxf(fmaxf(fmaxf(s[0][0], s[0][1]), fmaxf(s[0][2], s[0][3])),
                         fmaxf(fmaxf(s[1][0], s[1][1]), fmaxf(s[1][2], s[1][3])));
        pm = fmaxf(pm, __shfl_xor(pm, 16));
        pm = fmaxf(pm, __shfl_xor(pm, 32));
        float mn = fmaxf(m_s, pm);
        float al = __expf(m_s - mn);
        m_s = mn;
        f32x4 p0, p1;
#pragma unroll
        for (int r = 0; r < 4; ++r) {
            p0[r] = __expf(s[0][r] - mn);
            p1[r] = __expf(s[1][r] - mn);
        }
        float rs = (p0[0] + p0[1]) + (p0[2] + p0[3]) +
                   (p1[0] + p1[1]) + (p1[2] + p1[3]);
        rs += __shfl_xor(rs, 16);
        rs += __shfl_xor(rs, 32);
        l_s = l_s * al + rs;
        // rescale O rows (row query = lg*4+r); al for that query is in lane lg*4+r
        float alr[4];
#pragma unroll
        for (int r = 0; r < 4; ++r) alr[r] = __shfl(al, lg * 4 + r);
#pragma unroll
        for (int nt = 0; nt < 4; ++nt)
#pragma unroll
            for (int r = 0; r < 4; ++r) o[nt][r] *= alr[r];

        // P -> LDS, row = query lq, cols = keys (2 x b64 stores)
        bf16x4 q0, q1;
#pragma unroll
        for (int r = 0; r < 4; ++r) { q0[r] = (__bf16)p0[r]; q1[r] = (__bf16)p1[r]; }
        *(bf16x4*)&pw[lq * 40 + lg * 4]      = q0;
        *(bf16x4*)&pw[lq * 40 + 16 + lg * 4] = q1;
        asm volatile("" ::: "memory");
        bf16x8 pa = *(const bf16x8*)&pw[lq * 40 + lg * 8];
#pragma unroll
        for (int nt = 0; nt < 4; ++nt) {
            bf16x8 bv = *(const bf16x8*)(vf +
                (((size_t)(b * 64 + (s0 >> 5)) * 4 + nt) * 64 + lane) * 8);
            o[nt] = __builtin_amdgcn_mfma_f32_16x16x32_bf16(pa, bv, o[nt], 0, 0, 0);
        }
    }

    asm volatile("" ::: "memory");
#pragma unroll
    for (int nt = 0; nt < 4; ++nt)
#pragma unroll
        for (int r = 0; r < 4; ++r)
            olds[w][lg * 4 + r][nt * 16 + lq] = o[nt][r];
    if (lg == 0) {
        mlds[w][lq] = m_s;
        llds[w][lq] = l_s;
    }
    __syncthreads();

    int row = threadIdx.x >> 5;
    int col = (threadIdx.x & 31) * 2;
    float M = -1e30f;
#pragma unroll
    for (int w2 = 0; w2 < 8; ++w2) M = fmaxf(M, mlds[w2][row]);
    float L = 0.f, o0 = 0.f, o1 = 0.f;
#pragma unroll
    for (int w2 = 0; w2 < 8; ++w2) {
        float sc = __expf(mlds[w2][row] - M);
        L  += sc * llds[w2][row];
        o0 += sc * olds[w2][row][col];
        o1 += sc * olds[w2][row][col + 1];
    }
    float inv = 1.0f / L;
    float* ob = out + ((size_t)b * T_ + t0 + row) * HS_ + col;
    ob[0] = o0 * inv;
    ob[1] = o1 * inv;
}

extern "C" void kernel_launch(void* const* d_in, const int* in_sizes, int n_in,
                              void* d_out, int out_size, void* d_ws, size_t ws_size,
                              hipStream_t stream) {
    const float* x  = (const float*)d_in[0];
    const float* Wq = (const float*)d_in[1];
    const float* Wk = (const float*)d_in[2];
    const float* Wv = (const float*)d_in[3];
    char* ws = (char*)d_ws;
    __bf16* wt = (__bf16*)ws;                     // 393216 B
    __bf16* qf = (__bf16*)(ws + 393216);          // 2 MB
    __bf16* kf = (__bf16*)(ws + 2490368);         // 2 MB
    __bf16* vf = (__bf16*)(ws + 4587520);         // 2 MB
    float* out = (float*)d_out;

    wt_kernel<<<dim3(48), dim3(256), 0, stream>>>(Wq, Wk, Wv, wt);
    qkv_kernel<<<dim3(512), dim3(512), 0, stream>>>(x, wt, qf, kf, vf);
    attn_kernel<<<dim3(1024), dim3(512), 0, stream>>>(qf, kf, vf, out);
}